// Round 2
// baseline (366.395 us; speedup 1.0000x reference)
//
#include <hip/hip_runtime.h>
#include <hip/hip_cooperative_groups.h>
#include <hip/hip_bf16.h>
#include <math.h>

namespace cg = cooperative_groups;

#define N_NODES 3072
#define NPAD    3104    // V^T column stride: N + 32 zeroed pad cols (aligned PV loads)
#define DIM     256
#define NH      8
#define HD      32
#define E_EDGES 98304
#define B_GRAPHS 16
#define RCAP    96      // per-row bucket capacity (mean 32, 11-sigma margin; fixed seed)
#define MAXC    332     // fp32 score stride: 332*4=1328B rows (16B-aligned float4 P reads)
#define TR      16      // rows per attention tile
#define SCALE   0.17677669529663689f   // 1/sqrt(32)

typedef __attribute__((ext_vector_type(8))) short bf16x8;
typedef __attribute__((ext_vector_type(4))) float f32x4;
typedef __attribute__((ext_vector_type(4))) unsigned short ushort4v;

__device__ inline unsigned short f2b(float f) {
    __hip_bfloat16 h = __float2bfloat16(f);
    return *reinterpret_cast<unsigned short*>(&h);
}
__device__ inline float b2f(unsigned short u) {
    __hip_bfloat16 h = *reinterpret_cast<__hip_bfloat16*>(&u);
    return __bfloat162float(h);
}

// ======================= phase bodies (shared by mega + fallback) =============

__device__ inline void xsplit_body(int u, int t, const float* __restrict__ x,
                                   unsigned short* __restrict__ xh,
                                   unsigned short* __restrict__ xl) {
    const int gid = u * 256 + t;
    float4 v = ((const float4*)x)[gid];
    ushort4v h, l;
    float c[4] = {v.x, v.y, v.z, v.w};
    #pragma unroll
    for (int i = 0; i < 4; ++i) {
        unsigned short hi = f2b(c[i]);
        h[i] = hi;
        l[i] = f2b(c[i] - b2f(hi));
    }
    ((ushort4v*)xh)[gid] = h;
    ((ushort4v*)xl)[gid] = l;
}

__device__ inline void wtrans_body(int wb, int t,
                                   const float* __restrict__ Wq, const float* __restrict__ Wk,
                                   const float* __restrict__ Wv, const float* __restrict__ Wo,
                                   unsigned short* __restrict__ Wth,
                                   unsigned short* __restrict__ Wtl,
                                   float (*tile)[33]) {
    const int mat = wb >> 6, tidx = wb & 63;
    const int tk = (tidx >> 3) * 32, tn = (tidx & 7) * 32;
    const float* W = (mat == 0) ? Wq : (mat == 1) ? Wk : (mat == 2) ? Wv : Wo;
    const int kk = t >> 5, nn = t & 31;
    #pragma unroll
    for (int p = 0; p < 4; ++p)
        tile[nn][kk + p * 8] = W[(size_t)(tk + kk + p * 8) * DIM + tn + nn];
    __syncthreads();
    const int n = t >> 3, kq = (t & 7) * 4;
    ushort4v h, l;
    #pragma unroll
    for (int i = 0; i < 4; ++i) {
        float v = tile[n][kq + i];
        unsigned short hi = f2b(v);
        h[i] = hi;
        l[i] = f2b(v - b2f(hi));
    }
    size_t o = (size_t)mat * DIM * DIM + (size_t)(tn + n) * DIM + tk + kq;
    *(ushort4v*)(Wth + o) = h;
    *(ushort4v*)(Wtl + o) = l;
}

__device__ inline void vtpad_body(int i, const int* __restrict__ batch,
                                  unsigned short* __restrict__ VT,
                                  int* __restrict__ gstart) {
    VT[(size_t)(i >> 5) * NPAD + N_NODES + (i & 31)] = 0;   // i in [0, 8192)
    if (i < N_NODES) {
        int bb = batch[i];
        int bp = (i == 0) ? -1 : batch[i - 1];
        for (int g = bp + 1; g <= bb; ++g) gstart[g] = i;
        if (i == N_NODES - 1)
            for (int g = bb + 1; g <= B_GRAPHS; ++g) gstart[g] = N_NODES;
    }
}

__device__ inline void edge_body(int e, const float* __restrict__ ea,
                                 const float* __restrict__ We, const float* __restrict__ be,
                                 const int* __restrict__ erow, const int* __restrict__ ecolin,
                                 float* __restrict__ ebias, int* __restrict__ tcur,
                                 unsigned int* __restrict__ tbuck) {
    const int row = erow[e];
    const int col = ecolin[e];
    int pos = atomicAdd(&tcur[row], 1);
    if (pos < RCAP)
        tbuck[(size_t)row * RCAP + pos] = ((unsigned int)e << 12) | (unsigned int)col;
    float4 a = ((const float4*)ea)[e];
    #pragma unroll
    for (int h = 0; h < NH; ++h) {
        float bb = fmaf(a.x, We[0 * NH + h],
                   fmaf(a.y, We[1 * NH + h],
                   fmaf(a.z, We[2 * NH + h],
                   fmaf(a.w, We[3 * NH + h], be[h]))));
        ebias[(size_t)h * E_EDGES + e] = bb;
    }
}

// wave tile 16x32; u in [0,1152): bx=u%96 (32-row block), by=u/96, mat=by>>2.
__device__ inline void qkv_body(int u, int t,
                                const unsigned short* __restrict__ xh, const unsigned short* __restrict__ xl,
                                const unsigned short* __restrict__ Wth, const unsigned short* __restrict__ Wtl,
                                const float* __restrict__ bq, const float* __restrict__ bk,
                                const float* __restrict__ bv,
                                unsigned short* __restrict__ Qb, unsigned short* __restrict__ Kb,
                                unsigned short* __restrict__ VT) {
    const int w = t >> 6, lane = t & 63;
    const int l16 = lane & 15, lq = lane >> 4;
    const int bx = u % 96, by = u / 96;
    const int mat = by >> 2;
    const int rb = bx * 32 + (w & 1) * 16;
    const int nb = (by & 3) * 64 + (w >> 1) * 32;
    const unsigned short* Wh = Wth + (size_t)mat * DIM * DIM;
    const unsigned short* Wl = Wtl + (size_t)mat * DIM * DIM;

    f32x4 acc[2] = {{0,0,0,0},{0,0,0,0}};

    if (mat < 2) {                       // ---- Q/K: A = x rows, B = W^T rows
        const size_t arow = (size_t)(rb + l16) * DIM + (lq << 3);
        #pragma unroll
        for (int kc = 0; kc < 8; ++kc) {
            const int k = kc * 32;
            bf16x8 ah = *(const bf16x8*)(xh + arow + k);
            bf16x8 al = *(const bf16x8*)(xl + arow + k);
            #pragma unroll
            for (int ct = 0; ct < 2; ++ct) {
                const size_t bo_ = (size_t)(nb + ct * 16 + l16) * DIM + k + (lq << 3);
                bf16x8 bh = *(const bf16x8*)(Wh + bo_);
                bf16x8 bl = *(const bf16x8*)(Wl + bo_);
                acc[ct] = __builtin_amdgcn_mfma_f32_16x16x32_bf16(ah, bh, acc[ct], 0, 0, 0);
                acc[ct] = __builtin_amdgcn_mfma_f32_16x16x32_bf16(ah, bl, acc[ct], 0, 0, 0);
                acc[ct] = __builtin_amdgcn_mfma_f32_16x16x32_bf16(al, bh, acc[ct], 0, 0, 0);
            }
        }
        const float* bias = (mat == 0) ? bq : bk;
        unsigned short* outp = (mat == 0) ? Qb : Kb;
        #pragma unroll
        for (int ct = 0; ct < 2; ++ct) {
            const int n = nb + ct * 16 + l16;
            const float bvl = bias[n];
            #pragma unroll
            for (int r = 0; r < 4; ++r)
                outp[(size_t)(rb + lq * 4 + r) * DIM + n] = f2b(acc[ct][r] + bvl);
        }
    } else {                             // ---- V^T: A = Wv^T rows, B = x rows
        const size_t brow = (size_t)(rb + l16) * DIM + (lq << 3);
        #pragma unroll
        for (int kc = 0; kc < 8; ++kc) {
            const int k = kc * 32;
            bf16x8 bxh = *(const bf16x8*)(xh + brow + k);
            bf16x8 bxl = *(const bf16x8*)(xl + brow + k);
            #pragma unroll
            for (int ct = 0; ct < 2; ++ct) {
                const size_t ao_ = (size_t)(nb + ct * 16 + l16) * DIM + k + (lq << 3);
                bf16x8 awh = *(const bf16x8*)(Wh + ao_);
                bf16x8 awl = *(const bf16x8*)(Wl + ao_);
                acc[ct] = __builtin_amdgcn_mfma_f32_16x16x32_bf16(awh, bxh, acc[ct], 0, 0, 0);
                acc[ct] = __builtin_amdgcn_mfma_f32_16x16x32_bf16(awh, bxl, acc[ct], 0, 0, 0);
                acc[ct] = __builtin_amdgcn_mfma_f32_16x16x32_bf16(awl, bxh, acc[ct], 0, 0, 0);
            }
        }
        #pragma unroll
        for (int ct = 0; ct < 2; ++ct) {
            #pragma unroll
            for (int r = 0; r < 4; ++r) {
                const int ncol = nb + ct * 16 + lq * 4 + r;   // output channel (h*HD+kout)
                VT[(size_t)ncol * NPAD + rb + l16] = f2b(acc[ct][r] + bv[ncol]);
            }
        }
    }
}

// One (graph g, row-tile, head h) attention tile. P stored in place in s as fp32.
__device__ inline void attn_body(int g, int tile_, int h, int t,
                                 const unsigned short* __restrict__ Qb,
                                 const unsigned short* __restrict__ Kb,
                                 const unsigned short* __restrict__ VT,
                                 const int* __restrict__ gstart,
                                 const int* __restrict__ tcur,
                                 const unsigned int* __restrict__ tbuck,
                                 const float* __restrict__ ebias,
                                 unsigned short* __restrict__ preh,
                                 unsigned short* __restrict__ prel,
                                 float (*s)[MAXC], float* rowinv) {
    const int gs = gstart[g], ge = gstart[g + 1];
    const int row0 = gs + tile_ * TR;
    if (row0 >= ge) return;                       // block-uniform
    const int nrows = min(TR, ge - row0);
    const int ncols = ge - gs;
    const int ags   = gs & ~15;                   // aligned column base
    const int coff  = gs - ags;                   // 0..15 dead prefix cols
    const int tcols = coff + ncols;
    const int cpad  = (tcols + 31) & ~31;
    const int wave = t >> 6, lane = t & 63;
    const int l16 = lane & 15, lq = lane >> 4;

    // ---- QK^T via MFMA
    {
        int arow = min(row0 + l16, N_NODES - 1);
        const bf16x8 aq = *(const bf16x8*)(Qb + (size_t)arow * DIM + h * HD + (lq << 3));
        const int nchunk16 = (tcols + 15) >> 4;
        for (int j = wave; j < nchunk16; j += 4) {
            const int c0 = j << 4;
            int krow = min(ags + c0 + l16, N_NODES - 1);
            bf16x8 bk = *(const bf16x8*)(Kb + (size_t)krow * DIM + h * HD + (lq << 3));
            f32x4 d = {0.f, 0.f, 0.f, 0.f};
            d = __builtin_amdgcn_mfma_f32_16x16x32_bf16(aq, bk, d, 0, 0, 0);
            const int col = c0 + l16, rbase = lq * 4;
            #pragma unroll
            for (int r = 0; r < 4; ++r) s[rbase + r][col] = d[r] * SCALE;
        }
    }
    __syncthreads();

    // ---- edge-bias scatter
    {
        const int r = t >> 4, sub = t & 15;
        if (r < nrows) {
            const int cnt = min(tcur[row0 + r], RCAP);
            const unsigned int* bk = tbuck + (size_t)(row0 + r) * RCAP;
            for (int idx = sub; idx < cnt; idx += 16) {
                unsigned int p = bk[idx];
                int c = (int)(p & 0xFFFu) - gs;
                if (c >= 0 && c < ncols)
                    atomicAdd(&s[r][coff + c], ebias[(size_t)h * E_EDGES + (p >> 12)]);
            }
        }
    }
    __syncthreads();

    // ---- softmax, exp written back in place (fp32 P)
    {
        const int r = t >> 4, sub = t & 15;
        if (r < nrows) {
            float m = -INFINITY;
            for (int c = coff + sub; c < tcols; c += 16) m = fmaxf(m, s[r][c]);
            m = fmaxf(m, __shfl_xor(m, 1, 16));
            m = fmaxf(m, __shfl_xor(m, 2, 16));
            m = fmaxf(m, __shfl_xor(m, 4, 16));
            m = fmaxf(m, __shfl_xor(m, 8, 16));
            float sum = 0.f;
            for (int c = sub; c < cpad; c += 16) {
                float e = 0.f;
                if (c >= coff && c < tcols) e = __expf(s[r][c] - m);
                sum += e;
                s[r][c] = e;
            }
            sum += __shfl_xor(sum, 1, 16);
            sum += __shfl_xor(sum, 2, 16);
            sum += __shfl_xor(sum, 4, 16);
            sum += __shfl_xor(sum, 8, 16);
            if (sub == 0) rowinv[r] = 1.0f / sum;
        } else {
            for (int c = sub; c < cpad; c += 16) s[r][c] = 0.f;
        }
    }
    __syncthreads();

    // ---- PV via MFMA: A-frag = fp32 P from LDS, cvt in regs; B = V^T row
    f32x4 o = {0.f, 0.f, 0.f, 0.f};
    {
        const int half = wave >> 1, par = wave & 1;
        const int kout = l16 + (half << 4);
        const int nchunk32 = cpad >> 5;
        const unsigned short* vrow = VT + (size_t)(h * HD + kout) * NPAD + ags + (lq << 3);
        for (int j = par; j < nchunk32; j += 2) {
            const int c0 = j << 5;
            const float4 p0 = *(const float4*)&s[l16][c0 + (lq << 3)];
            const float4 p1 = *(const float4*)&s[l16][c0 + (lq << 3) + 4];
            bf16x8 ap;
            ap[0] = f2b(p0.x); ap[1] = f2b(p0.y); ap[2] = f2b(p0.z); ap[3] = f2b(p0.w);
            ap[4] = f2b(p1.x); ap[5] = f2b(p1.y); ap[6] = f2b(p1.z); ap[7] = f2b(p1.w);
            bf16x8 bv = *(const bf16x8*)(vrow + c0);
            o = __builtin_amdgcn_mfma_f32_16x16x32_bf16(ap, bv, o, 0, 0, 0);
        }
    }
    __syncthreads();
    {
        float* red = &s[0][0];       // [4 waves][16 rows][16 kout], stride 17
        const int rbase = lq * 4;
        #pragma unroll
        for (int r = 0; r < 4; ++r)
            red[((wave << 4) + rbase + r) * 17 + l16] = o[r];
    }
    __syncthreads();
    {
        const int row = t >> 4, kl = t & 15;
        if (row < nrows) {
            float* red = &s[0][0];
            float v0 = red[(row) * 17 + kl]        + red[(16 + row) * 17 + kl];
            float v1 = red[(32 + row) * 17 + kl]   + red[(48 + row) * 17 + kl];
            float sc = rowinv[row];
            size_t ob = (size_t)(row0 + row) * DIM + h * HD;
            float f0 = v0 * sc, f1 = v1 * sc;
            unsigned short h0 = f2b(f0), h1 = f2b(f1);
            preh[ob + kl]      = h0;
            preh[ob + 16 + kl] = h1;
            prel[ob + kl]      = f2b(f0 - b2f(h0));
            prel[ob + 16 + kl] = f2b(f1 - b2f(h1));
        }
    }
}

__device__ inline void out_body(int bxo, int byo, int t,
                                const unsigned short* __restrict__ preh,
                                const unsigned short* __restrict__ prel,
                                const unsigned short* __restrict__ Wth,
                                const unsigned short* __restrict__ Wtl,
                                const float* __restrict__ bo, float* __restrict__ out) {
    const int w = t >> 6, lane = t & 63;
    const int l16 = lane & 15, lq = lane >> 4;
    const int rb = bxo * 16;
    const int nb = byo * 128 + w * 32;
    const unsigned short* Wh = Wth + (size_t)3 * DIM * DIM;   // Wo^T
    const unsigned short* Wl = Wtl + (size_t)3 * DIM * DIM;

    f32x4 acc[2] = {{0,0,0,0},{0,0,0,0}};
    const size_t arow = (size_t)(rb + l16) * DIM + (lq << 3);

    #pragma unroll
    for (int kc = 0; kc < 8; ++kc) {
        const int k = kc * 32;
        bf16x8 ah = *(const bf16x8*)(preh + arow + k);
        bf16x8 al = *(const bf16x8*)(prel + arow + k);
        #pragma unroll
        for (int ct = 0; ct < 2; ++ct) {
            const size_t bo_ = (size_t)(nb + ct * 16 + l16) * DIM + k + (lq << 3);
            bf16x8 bh = *(const bf16x8*)(Wh + bo_);
            bf16x8 bl = *(const bf16x8*)(Wl + bo_);
            acc[ct] = __builtin_amdgcn_mfma_f32_16x16x32_bf16(ah, bh, acc[ct], 0, 0, 0);
            acc[ct] = __builtin_amdgcn_mfma_f32_16x16x32_bf16(ah, bl, acc[ct], 0, 0, 0);
            acc[ct] = __builtin_amdgcn_mfma_f32_16x16x32_bf16(al, bh, acc[ct], 0, 0, 0);
        }
    }

    #pragma unroll
    for (int ct = 0; ct < 2; ++ct) {
        const int n = nb + ct * 16 + l16;
        const float bvl = bo[n];
        #pragma unroll
        for (int r = 0; r < 4; ++r)
            out[(size_t)(rb + lq * 4 + r) * DIM + n] = acc[ct][r] + bvl;
    }
}

// ======================= mega kernel: all 4 stages, 3 grid syncs ==============
// __launch_bounds__(256,4): VGPR<=128 -> 4 blocks/CU -> 1024 co-resident blocks.
// LDS 21.3KB (7/CU, not limiting). Phase B overlaps edge bucketing with QKV MFMA
// (previously serialized across two kernel launches).
__global__ __launch_bounds__(256, 4) void mega(
    const float* __restrict__ x,
    const float* __restrict__ Wq, const float* __restrict__ Wk,
    const float* __restrict__ Wv, const float* __restrict__ Wo,
    const float* __restrict__ ea, const float* __restrict__ We,
    const float* __restrict__ be,
    const int* __restrict__ erow, const int* __restrict__ ecolin,
    const float* __restrict__ bq, const float* __restrict__ bk,
    const float* __restrict__ bv, const float* __restrict__ bo,
    const int* __restrict__ batch,
    unsigned short* __restrict__ xh, unsigned short* __restrict__ xl,
    unsigned short* __restrict__ Wth, unsigned short* __restrict__ Wtl,
    unsigned short* __restrict__ Qb, unsigned short* __restrict__ Kb,
    unsigned short* __restrict__ VT, unsigned short* __restrict__ preh,
    unsigned short* __restrict__ prel,
    float* __restrict__ ebias, int* __restrict__ gstart,
    int* __restrict__ tcur, unsigned int* __restrict__ tbuck,
    float* __restrict__ out)
{
    cg::grid_group grid = cg::this_grid();
    __shared__ __align__(16) float smem[TR * MAXC + TR];   // 21312 B, phase-shared
    const int t = threadIdx.x;
    const int G = gridDim.x;

    // ---- Phase A: x-split (768) | W-transpose (256) | VT-pad/gstart (32) | tcur zero (12)
    for (int u = blockIdx.x; u < 1068; u += G) {
        if (u < 768) {
            xsplit_body(u, t, x, xh, xl);
        } else if (u < 1024) {
            wtrans_body(u - 768, t, Wq, Wk, Wv, Wo, Wth, Wtl, (float(*)[33])smem);
            __syncthreads();             // guard tile reuse across loop iterations
        } else if (u < 1056) {
            vtpad_body((u - 1024) * 256 + t, batch, VT, gstart);
        } else {
            tcur[(u - 1056) * 256 + t] = 0;
        }
    }
    grid.sync();

    // ---- Phase B: edge bucket+bias (384) CONCURRENT WITH qkv mfma (1152)
    for (int u = blockIdx.x; u < 1536; u += G) {
        if (u < 384) edge_body(u * 256 + t, ea, We, be, erow, ecolin, ebias, tcur, tbuck);
        else         qkv_body(u - 384, t, xh, xl, Wth, Wtl, bq, bk, bv, Qb, Kb, VT);
    }
    grid.sync();

    // ---- Phase C: attention, 3072 (g,tile,head) units
    {
        float (*s)[MAXC] = (float(*)[MAXC])smem;
        float* rowinv = smem + TR * MAXC;
        for (int u = blockIdx.x; u < 3072; u += G) {
            const int g = u & 15, r2 = u >> 4;
            attn_body(g, r2 % 24, r2 / 24, t, Qb, Kb, VT, gstart, tcur, tbuck,
                      ebias, preh, prel, s, rowinv);
            __syncthreads();             // guard s[] reuse across loop iterations
        }
    }
    grid.sync();

    // ---- Phase D: output projection, 384 units
    for (int u = blockIdx.x; u < 384; u += G)
        out_body(u % 192, u / 192, t, preh, prel, Wth, Wtl, bo, out);
}

// ======================= fallback kernels (proven 5-dispatch path) ============

__global__ __launch_bounds__(256) void prep(
    const float* __restrict__ x,
    const float* __restrict__ Wq, const float* __restrict__ Wk,
    const float* __restrict__ Wv, const float* __restrict__ Wo,
    const float* __restrict__ ea, const float* __restrict__ We,
    const float* __restrict__ be,
    const int* __restrict__ erow, const int* __restrict__ ecolin,
    unsigned short* __restrict__ xh, unsigned short* __restrict__ xl,
    unsigned short* __restrict__ Wth, unsigned short* __restrict__ Wtl,
    unsigned short* __restrict__ VT, float* __restrict__ ebias,
    const int* __restrict__ batch, int* __restrict__ gstart,
    int* __restrict__ tcur, unsigned int* __restrict__ tbuck)
{
    __shared__ float tile[32][33];
    const int b = blockIdx.x, t = threadIdx.x;
    if (b < 768)        xsplit_body(b, t, x, xh, xl);
    else if (b < 1024)  wtrans_body(b - 768, t, Wq, Wk, Wv, Wo, Wth, Wtl, tile);
    else if (b < 1056)  vtpad_body((b - 1024) * 256 + t, batch, VT, gstart);
    else                edge_body((b - 1056) * 256 + t, ea, We, be, erow, ecolin,
                                  ebias, tcur, tbuck);
}

__global__ __launch_bounds__(256) void qkv_mfma(
    const unsigned short* __restrict__ xh, const unsigned short* __restrict__ xl,
    const unsigned short* __restrict__ Wth, const unsigned short* __restrict__ Wtl,
    const float* __restrict__ bq, const float* __restrict__ bk, const float* __restrict__ bv,
    unsigned short* __restrict__ Qb, unsigned short* __restrict__ Kb,
    unsigned short* __restrict__ VT)
{
    qkv_body(blockIdx.x, threadIdx.x, xh, xl, Wth, Wtl, bq, bk, bv, Qb, Kb, VT);
}

__global__ __launch_bounds__(256) void attn(
    const unsigned short* __restrict__ Qb, const unsigned short* __restrict__ Kb,
    const unsigned short* __restrict__ VT,
    const int* __restrict__ gstart,
    const int* __restrict__ tcur, const unsigned int* __restrict__ tbuck,
    const float* __restrict__ ebias,
    unsigned short* __restrict__ preh, unsigned short* __restrict__ prel)
{
    __shared__ __align__(16) float s[TR][MAXC];
    __shared__ float rowinv[TR];
    attn_body(blockIdx.x, blockIdx.y, blockIdx.z, threadIdx.x,
              Qb, Kb, VT, gstart, tcur, tbuck, ebias, preh, prel, s, rowinv);
}

__global__ __launch_bounds__(256) void out_mfma(
    const unsigned short* __restrict__ preh, const unsigned short* __restrict__ prel,
    const unsigned short* __restrict__ Wth, const unsigned short* __restrict__ Wtl,
    const float* __restrict__ bo, float* __restrict__ out)
{
    out_body(blockIdx.x, blockIdx.y, threadIdx.x, preh, prel, Wth, Wtl, bo, out);
}

// ---------------- launch ----------------
extern "C" void kernel_launch(void* const* d_in, const int* in_sizes, int n_in,
                              void* d_out, int out_size, void* d_ws, size_t ws_size,
                              hipStream_t stream) {
    const float* x   = (const float*)d_in[0];
    const float* ea  = (const float*)d_in[1];
    const float* Wq  = (const float*)d_in[2];  const float* bq = (const float*)d_in[3];
    const float* Wk  = (const float*)d_in[4];  const float* bk = (const float*)d_in[5];
    const float* Wv  = (const float*)d_in[6];  const float* bv = (const float*)d_in[7];
    const float* Wo  = (const float*)d_in[8];  const float* bo = (const float*)d_in[9];
    const float* We  = (const float*)d_in[10]; const float* be = (const float*)d_in[11];
    const int*   eidx  = (const int*)d_in[12];
    const int*   batch = (const int*)d_in[13];
    const int* erow   = eidx;
    const int* ecolin = eidx + E_EDGES;
    float* outp = (float*)d_out;

    const size_t ND = (size_t)N_NODES * DIM;     // 786432
    const size_t WD = (size_t)DIM * DIM;         // 65536

    unsigned short* Qb   = (unsigned short*)d_ws;
    unsigned short* Kb   = Qb + ND;
    unsigned short* VT   = Kb + ND;              // [256][NPAD]
    unsigned short* preh = VT + (size_t)DIM * NPAD;
    unsigned short* prel = preh + ND;
    unsigned short* xh   = prel + ND;
    unsigned short* xl   = xh + ND;
    unsigned short* Wth  = xl + ND;              // 4 * WD
    unsigned short* Wtl  = Wth + 4 * WD;
    unsigned int* tbuck  = (unsigned int*)(Wtl + 4 * WD);       // N_NODES * RCAP u32
    float* ebias  = (float*)(tbuck + (size_t)N_NODES * RCAP);   // [NH][E]
    int* tcur     = (int*)(ebias + (size_t)NH * E_EDGES);       // N_NODES
    int* gstart   = tcur + N_NODES;                             // B+1

    // One-time occupancy query (host-side, capture-safe). 0 => use fallback path.
    static int coopBlocks = -2;
    if (coopBlocks == -2) {
        int mb = 0;
        if (hipOccupancyMaxActiveBlocksPerMultiprocessor(&mb, mega, 256, 0) == hipSuccess
            && mb > 0) {
            coopBlocks = mb * 256;                // 256 CUs on MI355X
            if (coopBlocks > 3072) coopBlocks = 3072;
        } else {
            coopBlocks = 0;
        }
    }

    if (coopBlocks > 0) {
        void* args[] = {
            (void*)&x, (void*)&Wq, (void*)&Wk, (void*)&Wv, (void*)&Wo,
            (void*)&ea, (void*)&We, (void*)&be, (void*)&erow, (void*)&ecolin,
            (void*)&bq, (void*)&bk, (void*)&bv, (void*)&bo, (void*)&batch,
            (void*)&xh, (void*)&xl, (void*)&Wth, (void*)&Wtl,
            (void*)&Qb, (void*)&Kb, (void*)&VT, (void*)&preh, (void*)&prel,
            (void*)&ebias, (void*)&gstart, (void*)&tcur, (void*)&tbuck, (void*)&outp
        };
        hipError_t e = hipLaunchCooperativeKernel(mega, dim3(coopBlocks), dim3(256),
                                                  args, 0, stream);
        if (e == hipSuccess) return;
        coopBlocks = 0;                           // permanent fallback from now on
    }

    // ---- fallback: proven 5-dispatch path
    hipMemsetAsync(tcur, 0, N_NODES * sizeof(int), stream);
    prep<<<dim3(1440), dim3(256), 0, stream>>>(x, Wq, Wk, Wv, Wo, ea, We, be,
                                               erow, ecolin, xh, xl, Wth, Wtl,
                                               VT, ebias, batch, gstart, tcur, tbuck);
    qkv_mfma<<<dim3(1152), dim3(256), 0, stream>>>(xh, xl, Wth, Wtl, bq, bk, bv,
                                                   Qb, Kb, VT);
    attn<<<dim3(B_GRAPHS, 24, NH), dim3(256), 0, stream>>>(Qb, Kb, VT, gstart,
                                                           tcur, tbuck, ebias, preh, prel);
    out_mfma<<<dim3(192, 2), dim3(256), 0, stream>>>(preh, prel, Wth, Wtl, bo, outp);
}

// Round 3
// 154.571 us; speedup vs baseline: 2.3704x; 2.3704x over previous
//
#include <hip/hip_runtime.h>
#include <hip/hip_bf16.h>
#include <math.h>

#define N_NODES 3072
#define NPAD    3104    // V^T column stride: N + 32 zeroed pad cols (aligned PV loads)
#define DIM     256
#define NH      8
#define HD      32
#define E_EDGES 98304
#define B_GRAPHS 16
#define RCAP    96      // per-row bucket capacity (mean 32, 11-sigma margin; fixed seed)
#define MAXC    332     // fp32 score stride: 332*4=1328B rows (16B-aligned float4 P reads)
#define TR      16      // rows per attention tile
#define SCALE   0.17677669529663689f   // 1/sqrt(32)

typedef __attribute__((ext_vector_type(8))) short bf16x8;
typedef __attribute__((ext_vector_type(4))) float f32x4;
typedef __attribute__((ext_vector_type(4))) unsigned short ushort4v;

__device__ inline unsigned short f2b(float f) {
    __hip_bfloat16 h = __float2bfloat16(f);
    return *reinterpret_cast<unsigned short*>(&h);
}
__device__ inline float b2f(unsigned short u) {
    __hip_bfloat16 h = *reinterpret_cast<__hip_bfloat16*>(&u);
    return __bfloat162float(h);
}

// ======================= phase bodies (proven in R1) ==========================

__device__ inline void xsplit_body(int u, int t, const float* __restrict__ x,
                                   unsigned short* __restrict__ xh,
                                   unsigned short* __restrict__ xl) {
    const int gid = u * 256 + t;
    float4 v = ((const float4*)x)[gid];
    ushort4v h, l;
    float c[4] = {v.x, v.y, v.z, v.w};
    #pragma unroll
    for (int i = 0; i < 4; ++i) {
        unsigned short hi = f2b(c[i]);
        h[i] = hi;
        l[i] = f2b(c[i] - b2f(hi));
    }
    ((ushort4v*)xh)[gid] = h;
    ((ushort4v*)xl)[gid] = l;
}

__device__ inline void wtrans_body(int wb, int t,
                                   const float* __restrict__ Wq, const float* __restrict__ Wk,
                                   const float* __restrict__ Wv, const float* __restrict__ Wo,
                                   unsigned short* __restrict__ Wth,
                                   unsigned short* __restrict__ Wtl,
                                   float (*tile)[33]) {
    const int mat = wb >> 6, tidx = wb & 63;
    const int tk = (tidx >> 3) * 32, tn = (tidx & 7) * 32;
    const float* W = (mat == 0) ? Wq : (mat == 1) ? Wk : (mat == 2) ? Wv : Wo;
    const int kk = t >> 5, nn = t & 31;
    #pragma unroll
    for (int p = 0; p < 4; ++p)
        tile[nn][kk + p * 8] = W[(size_t)(tk + kk + p * 8) * DIM + tn + nn];
    __syncthreads();
    const int n = t >> 3, kq = (t & 7) * 4;
    ushort4v h, l;
    #pragma unroll
    for (int i = 0; i < 4; ++i) {
        float v = tile[n][kq + i];
        unsigned short hi = f2b(v);
        h[i] = hi;
        l[i] = f2b(v - b2f(hi));
    }
    size_t o = (size_t)mat * DIM * DIM + (size_t)(tn + n) * DIM + tk + kq;
    *(ushort4v*)(Wth + o) = h;
    *(ushort4v*)(Wtl + o) = l;
}

__device__ inline void vtpad_body(int i, const int* __restrict__ batch,
                                  unsigned short* __restrict__ VT,
                                  int* __restrict__ gstart) {
    VT[(size_t)(i >> 5) * NPAD + N_NODES + (i & 31)] = 0;   // i in [0, 8192)
    if (i < N_NODES) {
        int bb = batch[i];
        int bp = (i == 0) ? -1 : batch[i - 1];
        for (int g = bp + 1; g <= bb; ++g) gstart[g] = i;
        if (i == N_NODES - 1)
            for (int g = bb + 1; g <= B_GRAPHS; ++g) gstart[g] = N_NODES;
    }
}

__device__ inline void edge_body(int e, const float* __restrict__ ea,
                                 const float* __restrict__ We, const float* __restrict__ be,
                                 const int* __restrict__ erow, const int* __restrict__ ecolin,
                                 float* __restrict__ ebias, int* __restrict__ tcur,
                                 unsigned int* __restrict__ tbuck) {
    const int row = erow[e];
    const int col = ecolin[e];
    int pos = atomicAdd(&tcur[row], 1);
    if (pos < RCAP)
        tbuck[(size_t)row * RCAP + pos] = ((unsigned int)e << 12) | (unsigned int)col;
    float4 a = ((const float4*)ea)[e];
    #pragma unroll
    for (int h = 0; h < NH; ++h) {
        float bb = fmaf(a.x, We[0 * NH + h],
                   fmaf(a.y, We[1 * NH + h],
                   fmaf(a.z, We[2 * NH + h],
                   fmaf(a.w, We[3 * NH + h], be[h]))));
        ebias[(size_t)h * E_EDGES + e] = bb;
    }
}

// wave tile 16x32; u in [0,1152): bx=u%96 (32-row block), by=u/96, mat=by>>2.
__device__ inline void qkv_body(int u, int t,
                                const unsigned short* __restrict__ xh, const unsigned short* __restrict__ xl,
                                const unsigned short* __restrict__ Wth, const unsigned short* __restrict__ Wtl,
                                const float* __restrict__ bq, const float* __restrict__ bk,
                                const float* __restrict__ bv,
                                unsigned short* __restrict__ Qb, unsigned short* __restrict__ Kb,
                                unsigned short* __restrict__ VT) {
    const int w = t >> 6, lane = t & 63;
    const int l16 = lane & 15, lq = lane >> 4;
    const int bx = u % 96, by = u / 96;
    const int mat = by >> 2;
    const int rb = bx * 32 + (w & 1) * 16;
    const int nb = (by & 3) * 64 + (w >> 1) * 32;
    const unsigned short* Wh = Wth + (size_t)mat * DIM * DIM;
    const unsigned short* Wl = Wtl + (size_t)mat * DIM * DIM;

    f32x4 acc[2] = {{0,0,0,0},{0,0,0,0}};

    if (mat < 2) {                       // ---- Q/K: A = x rows, B = W^T rows
        const size_t arow = (size_t)(rb + l16) * DIM + (lq << 3);
        #pragma unroll
        for (int kc = 0; kc < 8; ++kc) {
            const int k = kc * 32;
            bf16x8 ah = *(const bf16x8*)(xh + arow + k);
            bf16x8 al = *(const bf16x8*)(xl + arow + k);
            #pragma unroll
            for (int ct = 0; ct < 2; ++ct) {
                const size_t bo_ = (size_t)(nb + ct * 16 + l16) * DIM + k + (lq << 3);
                bf16x8 bh = *(const bf16x8*)(Wh + bo_);
                bf16x8 bl = *(const bf16x8*)(Wl + bo_);
                acc[ct] = __builtin_amdgcn_mfma_f32_16x16x32_bf16(ah, bh, acc[ct], 0, 0, 0);
                acc[ct] = __builtin_amdgcn_mfma_f32_16x16x32_bf16(ah, bl, acc[ct], 0, 0, 0);
                acc[ct] = __builtin_amdgcn_mfma_f32_16x16x32_bf16(al, bh, acc[ct], 0, 0, 0);
            }
        }
        const float* bias = (mat == 0) ? bq : bk;
        unsigned short* outp = (mat == 0) ? Qb : Kb;
        #pragma unroll
        for (int ct = 0; ct < 2; ++ct) {
            const int n = nb + ct * 16 + l16;
            const float bvl = bias[n];
            #pragma unroll
            for (int r = 0; r < 4; ++r)
                outp[(size_t)(rb + lq * 4 + r) * DIM + n] = f2b(acc[ct][r] + bvl);
        }
    } else {                             // ---- V^T: A = Wv^T rows, B = x rows
        const size_t brow = (size_t)(rb + l16) * DIM + (lq << 3);
        #pragma unroll
        for (int kc = 0; kc < 8; ++kc) {
            const int k = kc * 32;
            bf16x8 bxh = *(const bf16x8*)(xh + brow + k);
            bf16x8 bxl = *(const bf16x8*)(xl + brow + k);
            #pragma unroll
            for (int ct = 0; ct < 2; ++ct) {
                const size_t ao_ = (size_t)(nb + ct * 16 + l16) * DIM + k + (lq << 3);
                bf16x8 awh = *(const bf16x8*)(Wh + ao_);
                bf16x8 awl = *(const bf16x8*)(Wl + ao_);
                acc[ct] = __builtin_amdgcn_mfma_f32_16x16x32_bf16(awh, bxh, acc[ct], 0, 0, 0);
                acc[ct] = __builtin_amdgcn_mfma_f32_16x16x32_bf16(awh, bxl, acc[ct], 0, 0, 0);
                acc[ct] = __builtin_amdgcn_mfma_f32_16x16x32_bf16(awl, bxh, acc[ct], 0, 0, 0);
            }
        }
        #pragma unroll
        for (int ct = 0; ct < 2; ++ct) {
            #pragma unroll
            for (int r = 0; r < 4; ++r) {
                const int ncol = nb + ct * 16 + lq * 4 + r;   // output channel (h*HD+kout)
                VT[(size_t)ncol * NPAD + rb + l16] = f2b(acc[ct][r] + bv[ncol]);
            }
        }
    }
}

// One (graph g, row-tile, head h) attention tile. P stored in place in s as fp32.
__device__ inline void attn_body(int g, int tile_, int h, int t,
                                 const unsigned short* __restrict__ Qb,
                                 const unsigned short* __restrict__ Kb,
                                 const unsigned short* __restrict__ VT,
                                 const int* __restrict__ gstart,
                                 const int* __restrict__ tcur,
                                 const unsigned int* __restrict__ tbuck,
                                 const float* __restrict__ ebias,
                                 unsigned short* __restrict__ preh,
                                 unsigned short* __restrict__ prel,
                                 float (*s)[MAXC], float* rowinv) {
    const int gs = gstart[g], ge = gstart[g + 1];
    const int row0 = gs + tile_ * TR;
    if (row0 >= ge) return;                       // block-uniform
    const int nrows = min(TR, ge - row0);
    const int ncols = ge - gs;
    const int ags   = gs & ~15;                   // aligned column base
    const int coff  = gs - ags;                   // 0..15 dead prefix cols
    const int tcols = coff + ncols;
    const int cpad  = (tcols + 31) & ~31;
    const int wave = t >> 6, lane = t & 63;
    const int l16 = lane & 15, lq = lane >> 4;

    // ---- QK^T via MFMA
    {
        int arow = min(row0 + l16, N_NODES - 1);
        const bf16x8 aq = *(const bf16x8*)(Qb + (size_t)arow * DIM + h * HD + (lq << 3));
        const int nchunk16 = (tcols + 15) >> 4;
        for (int j = wave; j < nchunk16; j += 4) {
            const int c0 = j << 4;
            int krow = min(ags + c0 + l16, N_NODES - 1);
            bf16x8 bk = *(const bf16x8*)(Kb + (size_t)krow * DIM + h * HD + (lq << 3));
            f32x4 d = {0.f, 0.f, 0.f, 0.f};
            d = __builtin_amdgcn_mfma_f32_16x16x32_bf16(aq, bk, d, 0, 0, 0);
            const int col = c0 + l16, rbase = lq * 4;
            #pragma unroll
            for (int r = 0; r < 4; ++r) s[rbase + r][col] = d[r] * SCALE;
        }
    }
    __syncthreads();

    // ---- edge-bias scatter
    {
        const int r = t >> 4, sub = t & 15;
        if (r < nrows) {
            const int cnt = min(tcur[row0 + r], RCAP);
            const unsigned int* bk = tbuck + (size_t)(row0 + r) * RCAP;
            for (int idx = sub; idx < cnt; idx += 16) {
                unsigned int p = bk[idx];
                int c = (int)(p & 0xFFFu) - gs;
                if (c >= 0 && c < ncols)
                    atomicAdd(&s[r][coff + c], ebias[(size_t)h * E_EDGES + (p >> 12)]);
            }
        }
    }
    __syncthreads();

    // ---- softmax, exp written back in place (fp32 P)
    {
        const int r = t >> 4, sub = t & 15;
        if (r < nrows) {
            float m = -INFINITY;
            for (int c = coff + sub; c < tcols; c += 16) m = fmaxf(m, s[r][c]);
            m = fmaxf(m, __shfl_xor(m, 1, 16));
            m = fmaxf(m, __shfl_xor(m, 2, 16));
            m = fmaxf(m, __shfl_xor(m, 4, 16));
            m = fmaxf(m, __shfl_xor(m, 8, 16));
            float sum = 0.f;
            for (int c = sub; c < cpad; c += 16) {
                float e = 0.f;
                if (c >= coff && c < tcols) e = __expf(s[r][c] - m);
                sum += e;
                s[r][c] = e;
            }
            sum += __shfl_xor(sum, 1, 16);
            sum += __shfl_xor(sum, 2, 16);
            sum += __shfl_xor(sum, 4, 16);
            sum += __shfl_xor(sum, 8, 16);
            if (sub == 0) rowinv[r] = 1.0f / sum;
        } else {
            for (int c = sub; c < cpad; c += 16) s[r][c] = 0.f;
        }
    }
    __syncthreads();

    // ---- PV via MFMA: A-frag = fp32 P from LDS, cvt in regs; B = V^T row
    f32x4 o = {0.f, 0.f, 0.f, 0.f};
    {
        const int half = wave >> 1, par = wave & 1;
        const int kout = l16 + (half << 4);
        const int nchunk32 = cpad >> 5;
        const unsigned short* vrow = VT + (size_t)(h * HD + kout) * NPAD + ags + (lq << 3);
        for (int j = par; j < nchunk32; j += 2) {
            const int c0 = j << 5;
            const float4 p0 = *(const float4*)&s[l16][c0 + (lq << 3)];
            const float4 p1 = *(const float4*)&s[l16][c0 + (lq << 3) + 4];
            bf16x8 ap;
            ap[0] = f2b(p0.x); ap[1] = f2b(p0.y); ap[2] = f2b(p0.z); ap[3] = f2b(p0.w);
            ap[4] = f2b(p1.x); ap[5] = f2b(p1.y); ap[6] = f2b(p1.z); ap[7] = f2b(p1.w);
            bf16x8 bv = *(const bf16x8*)(vrow + c0);
            o = __builtin_amdgcn_mfma_f32_16x16x32_bf16(ap, bv, o, 0, 0, 0);
        }
    }
    __syncthreads();
    {
        float* red = &s[0][0];       // [4 waves][16 rows][16 kout], stride 17
        const int rbase = lq * 4;
        #pragma unroll
        for (int r = 0; r < 4; ++r)
            red[((wave << 4) + rbase + r) * 17 + l16] = o[r];
    }
    __syncthreads();
    {
        const int row = t >> 4, kl = t & 15;
        if (row < nrows) {
            float* red = &s[0][0];
            float v0 = red[(row) * 17 + kl]        + red[(16 + row) * 17 + kl];
            float v1 = red[(32 + row) * 17 + kl]   + red[(48 + row) * 17 + kl];
            float sc = rowinv[row];
            size_t ob = (size_t)(row0 + row) * DIM + h * HD;
            float f0 = v0 * sc, f1 = v1 * sc;
            unsigned short h0 = f2b(f0), h1 = f2b(f1);
            preh[ob + kl]      = h0;
            preh[ob + 16 + kl] = h1;
            prel[ob + kl]      = f2b(f0 - b2f(h0));
            prel[ob + 16 + kl] = f2b(f1 - b2f(h1));
        }
    }
}

__device__ inline void out_body(int bxo, int byo, int t,
                                const unsigned short* __restrict__ preh,
                                const unsigned short* __restrict__ prel,
                                const unsigned short* __restrict__ Wth,
                                const unsigned short* __restrict__ Wtl,
                                const float* __restrict__ bo, float* __restrict__ out) {
    const int w = t >> 6, lane = t & 63;
    const int l16 = lane & 15, lq = lane >> 4;
    const int rb = bxo * 16;
    const int nb = byo * 128 + w * 32;
    const unsigned short* Wh = Wth + (size_t)3 * DIM * DIM;   // Wo^T
    const unsigned short* Wl = Wtl + (size_t)3 * DIM * DIM;

    f32x4 acc[2] = {{0,0,0,0},{0,0,0,0}};
    const size_t arow = (size_t)(rb + l16) * DIM + (lq << 3);

    #pragma unroll
    for (int kc = 0; kc < 8; ++kc) {
        const int k = kc * 32;
        bf16x8 ah = *(const bf16x8*)(preh + arow + k);
        bf16x8 al = *(const bf16x8*)(prel + arow + k);
        #pragma unroll
        for (int ct = 0; ct < 2; ++ct) {
            const size_t bo_ = (size_t)(nb + ct * 16 + l16) * DIM + k + (lq << 3);
            bf16x8 bh = *(const bf16x8*)(Wh + bo_);
            bf16x8 bl = *(const bf16x8*)(Wl + bo_);
            acc[ct] = __builtin_amdgcn_mfma_f32_16x16x32_bf16(ah, bh, acc[ct], 0, 0, 0);
            acc[ct] = __builtin_amdgcn_mfma_f32_16x16x32_bf16(ah, bl, acc[ct], 0, 0, 0);
            acc[ct] = __builtin_amdgcn_mfma_f32_16x16x32_bf16(al, bh, acc[ct], 0, 0, 0);
        }
    }

    #pragma unroll
    for (int ct = 0; ct < 2; ++ct) {
        const int n = nb + ct * 16 + l16;
        const float bvl = bo[n];
        #pragma unroll
        for (int r = 0; r < 4; ++r)
            out[(size_t)(rb + lq * 4 + r) * DIM + n] = acc[ct][r] + bvl;
    }
}

// ======================= node 1: x-split | W-trans | tcur zero ================
// grid 1036: [0,768) x-split, [768,1024) W-transpose, [1024,1036) tcur zero.
// tcur zeroing lives here (not a memset node): edges moved to node 2.
__global__ __launch_bounds__(256) void prep_a(
    const float* __restrict__ x,
    const float* __restrict__ Wq, const float* __restrict__ Wk,
    const float* __restrict__ Wv, const float* __restrict__ Wo,
    unsigned short* __restrict__ xh, unsigned short* __restrict__ xl,
    unsigned short* __restrict__ Wth, unsigned short* __restrict__ Wtl,
    int* __restrict__ tcur)
{
    __shared__ float tile[32][33];
    const int b = blockIdx.x, t = threadIdx.x;
    if (b < 768)        xsplit_body(b, t, x, xh, xl);
    else if (b < 1024)  wtrans_body(b - 768, t, Wq, Wk, Wv, Wo, Wth, Wtl, tile);
    else                tcur[(b - 1024) * 256 + t] = 0;
}

// ======================= node 2: edges | qkv mfma | VT-pad/gstart =============
// grid 1568: [0,384) edge bucket+bias (atomic latency hides under qkv MFMA),
// [384,1536) qkv (needs xh/xl/Wth/Wtl from node 1), [1536,1568) VT-pad/gstart.
__global__ __launch_bounds__(256) void stage2(
    const unsigned short* __restrict__ xh, const unsigned short* __restrict__ xl,
    const unsigned short* __restrict__ Wth, const unsigned short* __restrict__ Wtl,
    const float* __restrict__ bq, const float* __restrict__ bk,
    const float* __restrict__ bv,
    const float* __restrict__ ea, const float* __restrict__ We,
    const float* __restrict__ be,
    const int* __restrict__ erow, const int* __restrict__ ecolin,
    const int* __restrict__ batch,
    unsigned short* __restrict__ Qb, unsigned short* __restrict__ Kb,
    unsigned short* __restrict__ VT,
    float* __restrict__ ebias, int* __restrict__ gstart,
    int* __restrict__ tcur, unsigned int* __restrict__ tbuck)
{
    const int b = blockIdx.x, t = threadIdx.x;
    if (b < 384)        edge_body(b * 256 + t, ea, We, be, erow, ecolin, ebias, tcur, tbuck);
    else if (b < 1536)  qkv_body(b - 384, t, xh, xl, Wth, Wtl, bq, bk, bv, Qb, Kb, VT);
    else                vtpad_body((b - 1536) * 256 + t, batch, VT, gstart);
}

// ======================= node 3: attention ====================================
__global__ __launch_bounds__(256) void attn(
    const unsigned short* __restrict__ Qb, const unsigned short* __restrict__ Kb,
    const unsigned short* __restrict__ VT,
    const int* __restrict__ gstart,
    const int* __restrict__ tcur, const unsigned int* __restrict__ tbuck,
    const float* __restrict__ ebias,
    unsigned short* __restrict__ preh, unsigned short* __restrict__ prel)
{
    __shared__ __align__(16) float s[TR][MAXC];
    __shared__ float rowinv[TR];
    attn_body(blockIdx.x, blockIdx.y, blockIdx.z, threadIdx.x,
              Qb, Kb, VT, gstart, tcur, tbuck, ebias, preh, prel, s, rowinv);
}

// ======================= node 4: output projection ============================
__global__ __launch_bounds__(256) void out_mfma(
    const unsigned short* __restrict__ preh, const unsigned short* __restrict__ prel,
    const unsigned short* __restrict__ Wth, const unsigned short* __restrict__ Wtl,
    const float* __restrict__ bo, float* __restrict__ out)
{
    out_body(blockIdx.x, blockIdx.y, threadIdx.x, preh, prel, Wth, Wtl, bo, out);
}

// ---------------- launch ----------------
extern "C" void kernel_launch(void* const* d_in, const int* in_sizes, int n_in,
                              void* d_out, int out_size, void* d_ws, size_t ws_size,
                              hipStream_t stream) {
    const float* x   = (const float*)d_in[0];
    const float* ea  = (const float*)d_in[1];
    const float* Wq  = (const float*)d_in[2];  const float* bq = (const float*)d_in[3];
    const float* Wk  = (const float*)d_in[4];  const float* bk = (const float*)d_in[5];
    const float* Wv  = (const float*)d_in[6];  const float* bv = (const float*)d_in[7];
    const float* Wo  = (const float*)d_in[8];  const float* bo = (const float*)d_in[9];
    const float* We  = (const float*)d_in[10]; const float* be = (const float*)d_in[11];
    const int*   eidx  = (const int*)d_in[12];
    const int*   batch = (const int*)d_in[13];
    const int* erow   = eidx;
    const int* ecolin = eidx + E_EDGES;

    const size_t ND = (size_t)N_NODES * DIM;     // 786432
    const size_t WD = (size_t)DIM * DIM;         // 65536

    unsigned short* Qb   = (unsigned short*)d_ws;
    unsigned short* Kb   = Qb + ND;
    unsigned short* VT   = Kb + ND;              // [256][NPAD]
    unsigned short* preh = VT + (size_t)DIM * NPAD;
    unsigned short* prel = preh + ND;
    unsigned short* xh   = prel + ND;
    unsigned short* xl   = xh + ND;
    unsigned short* Wth  = xl + ND;              // 4 * WD
    unsigned short* Wtl  = Wth + 4 * WD;
    unsigned int* tbuck  = (unsigned int*)(Wtl + 4 * WD);       // N_NODES * RCAP u32
    float* ebias  = (float*)(tbuck + (size_t)N_NODES * RCAP);   // [NH][E]
    int* tcur     = (int*)(ebias + (size_t)NH * E_EDGES);       // N_NODES
    int* gstart   = tcur + N_NODES;                             // B+1

    prep_a<<<dim3(1036), dim3(256), 0, stream>>>(x, Wq, Wk, Wv, Wo,
                                                 xh, xl, Wth, Wtl, tcur);
    stage2<<<dim3(1568), dim3(256), 0, stream>>>(xh, xl, Wth, Wtl, bq, bk, bv,
                                                 ea, We, be, erow, ecolin, batch,
                                                 Qb, Kb, VT, ebias, gstart, tcur, tbuck);
    attn<<<dim3(B_GRAPHS, 24, NH), dim3(256), 0, stream>>>(Qb, Kb, VT, gstart,
                                                           tcur, tbuck, ebias, preh, prel);
    out_mfma<<<dim3(192, 2), dim3(256), 0, stream>>>(preh, prel, Wth, Wtl, bo, (float*)d_out);
}